// Round 8
// baseline (160.174 us; speedup 1.0000x reference)
//
#include <hip/hip_runtime.h>

#define NB 2048
#define NJ 22
#define ND 128
#define JD (NJ * ND)         // 2816 floats per batch of src/Y
#define ROW4 (JD / 4)        // 704 float4 per i-row
#define B4 (NJ * ROW4)       // 15488 float4 of out per batch
#define TOT4 (NB * B4)       // 31,719,424 float4 total

typedef float f32x4 __attribute__((ext_vector_type(4)));

// ---------------- Kernel A: Y[b][j][e] = sum_d src[b][j][d] * W[e][d] ----------------
__global__ __launch_bounds__(256, 4) void gemm_y(
    const float* __restrict__ src, const float* __restrict__ W,
    float* __restrict__ Y) {
  __shared__ float srcS[NJ * ND];  // [j][d]
  __shared__ float YS[NJ * ND];    // [j][e]

  const int b = blockIdx.x;
  const int t = threadIdx.x;
  const float* srcB = src + (size_t)b * JD;

  for (int idx = t; idx < JD / 4; idx += 256) {
    reinterpret_cast<f32x4*>(srcS)[idx] =
        reinterpret_cast<const f32x4*>(srcB)[idx];
  }

  const int e  = t & 127;  // output feature this thread owns
  const int dh = t >> 7;   // d-half (0/1)

  float w[64];
  {
    const f32x4* Wrow = reinterpret_cast<const f32x4*>(W + e * ND + dh * 64);
#pragma unroll
    for (int k = 0; k < 16; ++k) {
      f32x4 v = Wrow[k];
      w[4 * k + 0] = v.x; w[4 * k + 1] = v.y;
      w[4 * k + 2] = v.z; w[4 * k + 3] = v.w;
    }
  }
  __syncthreads();  // srcS ready

  for (int c = 0; c < 2; ++c) {  // two chunks of 11 rows: VGPR < 128
    float acc[11];
#pragma unroll
    for (int jj = 0; jj < 11; ++jj) {
      const int j = c * 11 + jj;
      const f32x4* s4 = reinterpret_cast<const f32x4*>(srcS + j * ND + dh * 64);
      float a = 0.f;
#pragma unroll
      for (int k = 0; k < 16; ++k) {
        f32x4 s = s4[k];  // wave-uniform address -> LDS broadcast
        a += s.x * w[4 * k + 0];
        a += s.y * w[4 * k + 1];
        a += s.z * w[4 * k + 2];
        a += s.w * w[4 * k + 3];
      }
      acc[jj] = a;
    }
    if (dh == 0) {
#pragma unroll
      for (int jj = 0; jj < 11; ++jj) YS[(c * 11 + jj) * ND + e] = acc[jj];
    }
    __syncthreads();
    if (dh == 1) {
#pragma unroll
      for (int jj = 0; jj < 11; ++jj) YS[(c * 11 + jj) * ND + e] += acc[jj];
    }
  }
  __syncthreads();  // YS complete

  f32x4* Yb4 = reinterpret_cast<f32x4*>(Y + (size_t)b * JD);
  const f32x4* YS4 = reinterpret_cast<const f32x4*>(YS);
  Yb4[t] = YS4[t];
  Yb4[t + 256] = YS4[t + 256];
  if (t < 192) Yb4[t + 512] = YS4[t + 512];
}

// ---------------- Kernel B: fill-pattern flat streamer ----------------
// out4[q] = Y4[b*704 + s] - Y4[b*704 + i*32 + e4] + bias4[e4]
// where q = b*15488 + i*704 + s, s = j*32 + e4, e4 = q & 31.
// Entire grid sweeps the output in flat address order (like fillBuffer):
// at any instant all CUs write within one contiguous ~8.4 MB window.
__global__ __launch_bounds__(256) void expand_flat(
    const float* __restrict__ Y, const float* __restrict__ bias,
    float* __restrict__ out) {
  const int nthr = gridDim.x * blockDim.x;  // divisible by 32
  const int q0 = blockIdx.x * blockDim.x + threadIdx.x;
  const f32x4* Y4 = reinterpret_cast<const f32x4*>(Y);
  f32x4* out4 = reinterpret_cast<f32x4*>(out);
  const f32x4 bb = reinterpret_cast<const f32x4*>(bias)[q0 & 31];

  for (int q = q0; q < TOT4; q += nthr) {
    const int b = q / B4;            // const-div -> mul_hi magic
    const int r = q - b * B4;
    const int i = r / ROW4;
    const int s = r - i * ROW4;      // j*32 + e4;  s ≡ q (mod 32)
    const int yb = b * ROW4;
    f32x4 yj = Y4[yb + s];                    // L1/L2-resident (23 MB)
    f32x4 yi = Y4[yb + i * 32 + (q & 31)];
    out4[q] = yj - yi + bb;
  }
}

extern "C" void kernel_launch(void* const* d_in, const int* in_sizes, int n_in,
                              void* d_out, int out_size, void* d_ws, size_t ws_size,
                              hipStream_t stream) {
  const float* src  = (const float*)d_in[0];  // [2048, 22, 128] f32
  const float* W    = (const float*)d_in[1];  // [128, 128] f32, W[e][d]
  const float* bias = (const float*)d_in[2];  // [128] f32
  float* out = (float*)d_out;                 // [2048, 22, 22, 128] f32
  float* Yw  = (float*)d_ws;                  // [2048, 22, 128] f32 = 23.1 MB

  gemm_y<<<NB, 256, 0, stream>>>(src, W, Yw);
  expand_flat<<<2048, 256, 0, stream>>>(Yw, bias, out);
}